// Round 11
// baseline (172.469 us; speedup 1.0000x reference)
//
#include <hip/hip_runtime.h>
#include <hip/hip_bf16.h>
#include <cstdint>

typedef unsigned char u8;
typedef float floatx4 __attribute__((ext_vector_type(4)));
typedef int intx8 __attribute__((ext_vector_type(8)));

__device__ __forceinline__ void gld_lds16(const void* g, void* l) {
    __builtin_amdgcn_global_load_lds(
        (const __attribute__((address_space(1))) unsigned int*)g,
        (__attribute__((address_space(3))) unsigned int*)l, 16, 0, 0);
}

// fp8 e4m3 (OCP) converts
__device__ __forceinline__ u8 f2fp8(float v) {
    return (u8)(__builtin_amdgcn_cvt_pk_fp8_f32(v, v, 0, false) & 0xff);
}
__device__ __forceinline__ unsigned int pack4_fp8(float a, float b, float c, float d) {
    unsigned int u = __builtin_amdgcn_cvt_pk_fp8_f32(a, b, 0, false);
    u = __builtin_amdgcn_cvt_pk_fp8_f32(c, d, u, true);
    return u;
}

// 32B fragment: two swizzled 16B granules -> v8i32 (LDS, 128B rows)
__device__ __forceinline__ intx8 ld_frag(const u8* p, int lo, int hi) {
    uint4 a = *(const uint4*)(p + lo);
    uint4 b = *(const uint4*)(p + hi);
    intx8 r;
    r[0] = a.x; r[1] = a.y; r[2] = a.z; r[3] = a.w;
    r[4] = b.x; r[5] = b.y; r[6] = b.z; r[7] = b.w;
    return r;
}
// 32B fragment straight from global (contiguous; coalesced under tiled layout)
__device__ __forceinline__ intx8 ld_frag_g(const u8* p) {
    uint4 a = *(const uint4*)(p);
    uint4 b = *(const uint4*)(p + 16);
    intx8 r;
    r[0] = a.x; r[1] = a.y; r[2] = a.z; r[3] = a.w;
    r[4] = b.x; r[5] = b.y; r[6] = b.z; r[7] = b.w;
    return r;
}

// ---------------------------------------------------------------------------
// Tiled fp8 layouts (per batch, 512KB each):
//   hT,q,k : addr = rb*8192 + cb*512 + ln*32 + [0,32)   rb=pos/16, cb=chan/32
//   v      : addr = chb*16384 + mq*512 + ln*32 + [0,32) chb=chan/16, mq=pos/32
//   wob    : addr = (oc/16)*8192 + (c/32)*512 + (oc%16)*32 + c%32  [512x512]
// A wave's MFMA fragment load (4 q4-groups x 16 ln x 32B) is 2KB contiguous.
// wqkv stays ROW-major [1536x512] (consumed via swizzled LDS staging).
//
// __launch_bounds__ empirical rule (rounds 5/8/9/10): VGPR cap = 256/arg2,
// regardless of block size. arg2=1 -> cap 256 (what register-heavy kernels
// need); arg2>=2 spills anything above 256/arg2.
// ---------------------------------------------------------------------------

// ---------------------------------------------------------------------------
// Setup: blocks 0..511 = one-pass GroupNorm (x fp32 -> hT TILED fp8);
// blocks 512..4607 = weight convert (wqkv row-major; wob tiled).
// ---------------------------------------------------------------------------
__global__ __launch_bounds__(256) void setup_kernel(
    const float* __restrict__ x, const float* __restrict__ gs,
    const float* __restrict__ gb,
    const float* __restrict__ wq, const float* __restrict__ wk,
    const float* __restrict__ wv, const float* __restrict__ wo,
    const float* __restrict__ bq, const float* __restrict__ bk,
    const float* __restrict__ bv,
    u8* __restrict__ hT, u8* __restrict__ wqkv, u8* __restrict__ wob,
    float* __restrict__ bqkv)
{
    const int t = threadIdx.x;
    if (blockIdx.x >= 512) {
        int i = (blockIdx.x - 512) * 256 + t;   // 0 .. 1048575
        if (i < 786432) {
            int which = i >> 18;
            int off = i & 262143;
            const float* src = which == 0 ? wq : which == 1 ? wk : wv;
            wqkv[i] = f2fp8(src[off]);
        } else {
            int i2 = i - 786432;                // [512 x 512] -> tiled
            int row = i2 >> 9, col = i2 & 511;
            wob[(long long)(row >> 4) * 8192 + (col >> 5) * 512
                + (row & 15) * 32 + (col & 31)] = f2fp8(wo[i2] * 262144.0f);  // x 2^18
        }
        if (i < 1536)
            bqkv[i] = i < 512 ? bq[i] : (i < 1024 ? bk[i - 512] : bv[i - 1024]);
        return;
    }
    const int b = blockIdx.x >> 5;
    const int g = blockIdx.x & 31;
    const int wave = t >> 6, lane = t & 63;
    const float4* x4 = (const float4*)(x + ((long long)b * 512 + g * 16) * 1024);

    // one pass: 16 channels x 4 positions per thread, kept in registers
    float4 v[16];
    float s1 = 0.f, s2 = 0.f;
#pragma unroll
    for (int i = 0; i < 16; ++i) {
        v[i] = x4[i * 256 + t];
        s1 += v[i].x + v[i].y + v[i].z + v[i].w;
        s2 += v[i].x * v[i].x + v[i].y * v[i].y + v[i].z * v[i].z + v[i].w * v[i].w;
    }
#pragma unroll
    for (int m = 32; m; m >>= 1) {
        s1 += __shfl_xor(s1, m, 64);
        s2 += __shfl_xor(s2, m, 64);
    }
    __shared__ float red[2][4];
    __shared__ float stats[2];
    if (lane == 0) { red[0][wave] = s1; red[1][wave] = s2; }
    __syncthreads();
    if (t == 0) {
        float a = red[0][0] + red[0][1] + red[0][2] + red[0][3];
        float q = red[1][0] + red[1][1] + red[1][2] + red[1][3];
        float mu = a * (1.0f / 16384.0f);
        float var = q * (1.0f / 16384.0f) - mu * mu;
        stats[0] = mu;
        stats[1] = rsqrtf(var + 1e-5f);
    }
    __syncthreads();
    const float mu = stats[0], rs = stats[1];

#pragma unroll
    for (int i = 0; i < 16; ++i) {
        const float sc = gs[g * 16 + i] * rs;
        const float bi = gb[g * 16 + i] - mu * sc;
        v[i].x = v[i].x * sc + bi;
        v[i].y = v[i].y * sc + bi;
        v[i].z = v[i].z * sc + bi;
        v[i].w = v[i].w * sc + bi;
    }
    // TILED fp8 write: pos = 4t+r, chans g*16..g*16+15 = half of granule g>>1
    u8* hb = hT + (long long)b * 524288 + (g >> 1) * 512 + (g & 1) * 16;
#pragma unroll
    for (int r = 0; r < 4; ++r) {
        const int pos = 4 * t + r;
        uint4 o;
        o.x = pack4_fp8(v[0][r],  v[1][r],  v[2][r],  v[3][r]);
        o.y = pack4_fp8(v[4][r],  v[5][r],  v[6][r],  v[7][r]);
        o.z = pack4_fp8(v[8][r],  v[9][r],  v[10][r], v[11][r]);
        o.w = pack4_fp8(v[12][r], v[13][r], v[14][r], v[15][r]);
        *(uint4*)(hb + (long long)(pos >> 4) * 8192 + (pos & 15) * 32) = o;
    }
}

// ---------------------------------------------------------------------------
// QKV GEMM, stage-B-once: C[pos,oc] = sum_c hT[pos,c] * wqkv[oc,c].
// 128x128 tile, 4 waves 64x64. B-tile [128 oc x 512] staged to LDS ONCE via
// swizzled global_load_lds (16 chunks, 1 barrier); A-fragments direct from
// L2 (tiled hT, 2KB/wave coalesced); 64 MFMAs with no inner barriers.
// Epilogue = fused QKV fp8 (+bias) into tiled q/k/v layouts (unchanged).
// ---------------------------------------------------------------------------
__global__ __launch_bounds__(256, 1) void gemm_qkv(
    const u8* __restrict__ A,          // hT tiled, stride 524288/batch
    const u8* __restrict__ B,          // wqkv row-major [1536 x 512]
    u8* __restrict__ Cq, u8* __restrict__ Ck, u8* __restrict__ Cv,
    const float* __restrict__ bias)
{
    __shared__ __align__(16) u8 smem[65536];   // B-tile; epilogue reuses [0,18432)
    const int tid = threadIdx.x;
    const int l = tid & 63;
    const int wave = tid >> 6;
    const int wm = wave >> 1, wn = wave & 1;
    const int bm = blockIdx.x, bn = blockIdx.y, b = blockIdx.z;

    const int q4 = l >> 4;
    const int ln = l & 15;
    const int glo = ((2 * q4) ^ (l & 7)) * 16;
    const int ghi = ((2 * q4 + 1) ^ (l & 7)) * 16;
    const int lo32 = ln * 32;

    // ---- stage B-tile: 16 chunks of [32 rows x 128 B], XOR'd granules ----
    const int srow = wave * 8 + (l >> 3);               // 0..31
    const int sg = ((l & 7) ^ ((l >> 3) & 7)) * 16;     // pre-swizzled source
    const u8* Bb = B + (long long)bn * 128 * 512;
    const int ldst = wave * 1024;                        // + lane*16 implicit
#pragma unroll
    for (int kc = 0; kc < 4; ++kc)
#pragma unroll
        for (int rc = 0; rc < 4; ++rc)
            gld_lds16(Bb + (long long)(rc * 32 + srow) * 512 + kc * 128 + sg,
                      smem + kc * 16384 + rc * 4096 + ldst);

    // hoist kc=0 A-fragments above the barrier (L2 latency overlaps staging)
    const u8* Ab = A + (long long)b * 524288 + (long long)(bm * 8 + wm * 4) * 8192;
    intx8 af0[4];
#pragma unroll
    for (int i = 0; i < 4; ++i)
        af0[i] = ld_frag_g(Ab + (long long)i * 8192 + q4 * 512 + lo32);

    __syncthreads();   // B-tile resident

    floatx4 acc[4][4] = {};
#pragma unroll
    for (int kc = 0; kc < 4; ++kc) {
        intx8 bfr[4];
#pragma unroll
        for (int j = 0; j < 4; ++j)
            bfr[j] = ld_frag(smem + kc * 16384 + (wn * 64 + j * 16 + ln) * 128,
                             glo, ghi);
#pragma unroll
        for (int i = 0; i < 4; ++i) {
            intx8 af = (kc == 0) ? af0[i]
                : ld_frag_g(Ab + (long long)i * 8192 + (kc * 4 + q4) * 512 + lo32);
#pragma unroll
            for (int j = 0; j < 4; ++j)
                acc[i][j] = __builtin_amdgcn_mfma_scale_f32_16x16x128_f8f6f4(
                    af, bfr[j], acc[i][j], 0, 0, 0, 127, 0, 127);
        }
    }

    __syncthreads();   // B-tile dead; epilogue may overwrite smem

    // ---------------- epilogue: fused QKV fp8 (+bias), tiled outputs ----------
    // C/D layout: col=lane&15, row=(lane>>4)*4+reg
    {
        const int which = bn >> 2;     // 0=q 1=k 2=v
        u8* tile = smem;               // q/k: [pos 128][chan,144]; v: [chan 128][pos,144]
#pragma unroll
        for (int i = 0; i < 4; ++i) {
            const int rl = wm * 64 + i * 16 + q4 * 4;
#pragma unroll
            for (int j = 0; j < 4; ++j) {
                const int cl = wn * 64 + j * 16 + ln;
                const float badd = bias[bn * 128 + cl];
                if (which == 2) {
                    // col-major fill: rows rl..rl+3 contiguous -> one packed u32
                    *(unsigned int*)(tile + cl * 144 + rl) =
                        pack4_fp8(acc[i][j][0] + badd, acc[i][j][1] + badd,
                                  acc[i][j][2] + badd, acc[i][j][3] + badd);
                } else {
#pragma unroll
                    for (int r = 0; r < 4; ++r)
                        tile[(rl + r) * 144 + cl] = f2fp8(acc[i][j][r] + badd);
                }
            }
        }
        __syncthreads();
        // Tiled write-out: per wave-iter 1KB contiguous.
        const int w2  = wave >> 1;                 // 0..1
        const int cbl = (wave & 1) * 2 + (l >> 5); // 0..3
        const int lnw = (l >> 1) & 15;
        const int g16 = (l & 1) * 16;
#pragma unroll
        for (int p = 0; p < 4; ++p) {
            const int rtile = p * 2 + w2;          // 0..7
            uint4 dd = *(const uint4*)(tile + (rtile * 16 + lnw) * 144 + cbl * 32 + g16);
            u8* dst;
            if (which == 0)
                dst = Cq + (long long)b * 524288 + (long long)(bm * 8 + rtile) * 8192
                      + ((bn & 3) * 4 + cbl) * 512 + lnw * 32 + g16;
            else if (which == 1)
                dst = Ck + (long long)b * 524288 + (long long)(bm * 8 + rtile) * 8192
                      + ((bn & 3) * 4 + cbl) * 512 + lnw * 32 + g16;
            else
                dst = Cv + (long long)b * 524288 + (long long)((bn & 3) * 8 + rtile) * 16384
                      + (long long)(bm * 4 + cbl) * 512 + lnw * 32 + g16;
            *(uint4*)dst = dd;
        }
    }
}

// ---------------------------------------------------------------------------
// Fused attention + output projection (4-wave, k-prefetch): per block =
// (one batch, 32 q-rows), 256 threads. launch_bounds(256,1): VGPR cap 256 —
// (256,2) capped at 128 and spilled the kreg prefetch (round 10: WRITE +3.6MB).
// Per m-tile: QK (kreg, load-free) -> issue vA -> exp -> E tile (dbuf) ->
// barrier -> prefetch kreg(mt+1) -> PV (vA/vB direct L2).
// Phase 2: hv -> fp8 swizzled LDS, out = wo_s . hv^T + bo + x.
// ---------------------------------------------------------------------------
__global__ __launch_bounds__(256, 1) void attn_out(
    const u8* __restrict__ qg, const u8* __restrict__ kg,
    const u8* __restrict__ vg, const u8* __restrict__ wot,
    const float* __restrict__ bo, const float* __restrict__ xg,
    float* __restrict__ outg)
{
    __shared__ __align__(16) u8 smem[25088];  // E dbuf 8K | psum 512 | HV 16K
    const int tid = threadIdx.x;
    const int l = tid & 63;
    const int w = tid >> 6;
    // XCD-aware swizzle: all 32 q-blocks of a batch pair land on one XCD (d%8)
    const int d = blockIdx.x;
    const int b  = (d & 7) * 2 + ((d >> 8) & 1);
    const int bq = (d >> 3) & 31;

    const u8* qb = qg + (long long)b * 524288 + (long long)(bq * 2) * 8192;
    const u8* kb = kg + (long long)b * 524288;
    const u8* vb = vg + (long long)b * 524288;

    const int q4 = l >> 4;
    const int ln = l & 15;
    const int glo = ((2 * q4) ^ (l & 7)) * 16;
    const int ghi = ((2 * q4 + 1) ^ (l & 7)) * 16;
    const int lo32 = ln * 32;

    // q -> registers once (tiled: rb = bq*2 + j, cb = kc*4 + q4)
    intx8 qf[2][4];
#pragma unroll
    for (int j = 0; j < 2; ++j)
#pragma unroll
        for (int kc = 0; kc < 4; ++kc)
            qf[j][kc] = ld_frag_g(qb + j * 8192 + (kc * 4 + q4) * 512 + lo32);

    // k register double-buffer: fragments for the CURRENT m-tile
    intx8 kreg[2][4];
#pragma unroll
    for (int i = 0; i < 2; ++i)
#pragma unroll
        for (int kc = 0; kc < 4; ++kc)
            kreg[i][kc] = ld_frag_g(kb + (long long)(w * 2 + i) * 8192
                                       + (kc * 4 + q4) * 512 + lo32);

    floatx4 acc_pv[8][2] = {};
    float psum[2] = {0.f, 0.f};
    const float scale = 0.044194173824159216f;   // 1/sqrt(512)

    for (int mt = 0; mt < 8; ++mt) {
        u8* E = smem + (mt & 1) * 4096;
        // ---- QK^T: all operands in registers, zero loads ----
        floatx4 acc_s[2][2] = {};
#pragma unroll
        for (int kc = 0; kc < 4; ++kc)
#pragma unroll
            for (int i = 0; i < 2; ++i)
#pragma unroll
                for (int j = 0; j < 2; ++j)
                    acc_s[i][j] = __builtin_amdgcn_mfma_scale_f32_16x16x128_f8f6f4(
                        kreg[i][kc], qf[j][kc], acc_s[i][j], 0, 0, 0, 127, 0, 127);
        // ---- issue v loads early (latency hides under exp + barrier) ----
        intx8 vfA[4], vfB[4];
        const u8* vrow = vb + (long long)(w * 8) * 16384 + (mt * 4 + q4) * 512 + lo32;
#pragma unroll
        for (int i = 0; i < 4; ++i)
            vfA[i] = ld_frag_g(vrow + (long long)i * 16384);
        // ---- exp + pack -> swizzled E tile [32 n x 128 m] ----
#pragma unroll
        for (int i = 0; i < 2; ++i) {
#pragma unroll
            for (int j = 0; j < 2; ++j) {
                float e0 = __expf(acc_s[i][j][0] * scale);
                float e1 = __expf(acc_s[i][j][1] * scale);
                float e2 = __expf(acc_s[i][j][2] * scale);
                float e3 = __expf(acc_s[i][j][3] * scale);
                psum[j] += e0 + e1 + e2 + e3;
                const int n = j * 16 + ln;
                const int m0 = w * 32 + i * 16 + q4 * 4;
                *(unsigned int*)(E + n * 128 + (m0 ^ ((n & 7) * 16))) =
                    pack4_fp8(e0 * 0.25f, e1 * 0.25f, e2 * 0.25f, e3 * 0.25f);
            }
        }
        __syncthreads();          // E visible; dbuf makes this the ONLY barrier
        // ---- prefetch NEXT m-tile's k fragments (hide under PV MFMAs) ----
        if (mt < 7) {
            const u8* kn = kb + (long long)((mt + 1) * 8 + w * 2) * 8192
                              + q4 * 512 + lo32;
#pragma unroll
            for (int i = 0; i < 2; ++i)
#pragma unroll
                for (int kc = 0; kc < 4; ++kc)
                    kreg[i][kc] = ld_frag_g(kn + (long long)i * 8192 + kc * 2048);
        }
        // ---- PV: acc_pv[c,n] += v[c,m] . E[n,m] ----
#pragma unroll
        for (int i = 0; i < 4; ++i)
            vfB[i] = ld_frag_g(vrow + (long long)(i + 4) * 16384);
        intx8 ef[2];
#pragma unroll
        for (int j = 0; j < 2; ++j)
            ef[j] = ld_frag(E + (j * 16 + ln) * 128, glo, ghi);
#pragma unroll
        for (int i = 0; i < 4; ++i)
#pragma unroll
            for (int j = 0; j < 2; ++j)
                acc_pv[i][j] = __builtin_amdgcn_mfma_scale_f32_16x16x128_f8f6f4(
                    vfA[i], ef[j], acc_pv[i][j], 0, 0, 0, 127, 0, 127);
#pragma unroll
        for (int i = 0; i < 4; ++i)
#pragma unroll
            for (int j = 0; j < 2; ++j)
                acc_pv[i + 4][j] = __builtin_amdgcn_mfma_scale_f32_16x16x128_f8f6f4(
                    vfB[i], ef[j], acc_pv[i + 4][j], 0, 0, 0, 127, 0, 127);
    }

    // psum: sum the 4 q4-groups (lanes ^16, ^32), then across waves via LDS
#pragma unroll
    for (int j = 0; j < 2; ++j) {
        psum[j] += __shfl_xor(psum[j], 16, 64);
        psum[j] += __shfl_xor(psum[j], 32, 64);
    }
    float* sb = (float*)(smem + 8192);   // [4 waves][32 n]
    if (l < 16) {
        sb[w * 32 + l]      = psum[0];
        sb[w * 32 + 16 + l] = psum[1];
    }
    __syncthreads();
    float rln[2];
#pragma unroll
    for (int j = 0; j < 2; ++j) {
        const int n = j * 16 + ln;
        rln[j] = 4.0f / (sb[n] + sb[32 + n] + sb[64 + n] + sb[96 + n]);
    }

    // ---- Phase 2a: hv -> fp8 swizzled LDS subtiles (per wave: 128 chans) ----
    u8* HV = smem + 8704;
#pragma unroll
    for (int i = 0; i < 8; ++i) {
#pragma unroll
        for (int j = 0; j < 2; ++j) {
            const int n = j * 16 + ln;
            const int m0 = i * 16 + q4 * 4;   // byte offset within subtile row
            *(unsigned int*)(HV + w * 4096 + n * 128 + (m0 ^ ((n & 7) * 16))) =
                pack4_fp8(acc_pv[i][j][0] * rln[j], acc_pv[i][j][1] * rln[j],
                          acc_pv[i][j][2] * rln[j], acc_pv[i][j][3] * rln[j]);
        }
    }
    // hoist kc=0 wo fragments above the barrier (L2 latency overlaps sync)
    intx8 wo0[2];
#pragma unroll
    for (int rb = 0; rb < 2; ++rb)
        wo0[rb] = ld_frag_g(wot + (long long)(w * 8 + rb) * 8192 + q4 * 512 + lo32);
    __syncthreads();

    // ---- Phase 2b: out = wo_s . hv^T: per wave 128 oc x 32 n, K=512 ----
    floatx4 acc2[8][2] = {};
#pragma unroll
    for (int kc = 0; kc < 4; ++kc) {
        intx8 hvf[2];
#pragma unroll
        for (int j = 0; j < 2; ++j)
            hvf[j] = ld_frag(HV + kc * 4096 + (j * 16 + ln) * 128, glo, ghi);
#pragma unroll
        for (int rb = 0; rb < 8; ++rb) {
            intx8 wof = (kc == 0 && rb < 2) ? wo0[rb]
                : ld_frag_g(wot + (long long)(w * 8 + rb) * 8192
                                + (kc * 4 + q4) * 512 + lo32);
#pragma unroll
            for (int j = 0; j < 2; ++j)
                acc2[rb][j] = __builtin_amdgcn_mfma_scale_f32_16x16x128_f8f6f4(
                    wof, hvf[j], acc2[rb][j], 0, 0, 0, 127, 0, 127);
        }
    }

    // ---- epilogue: out[b][oc][n] = acc2*2^-18 + bo[oc] + x[b][oc][n] ----
    const float osc = 3.814697265625e-06f;       // 2^-18
    const float* xb = xg + (long long)b * 524288;
    float* og = outg + (long long)b * 524288;
    const int n0 = bq * 32;
#pragma unroll
    for (int rb = 0; rb < 8; ++rb) {
        const int oc0 = w * 128 + rb * 16 + q4 * 4;
#pragma unroll
        for (int j = 0; j < 2; ++j) {
            const int n = n0 + j * 16 + ln;
#pragma unroll
            for (int r = 0; r < 4; ++r) {
                const int oc = oc0 + r;
                og[(long long)oc * 1024 + n] =
                    acc2[rb][j][r] * osc + bo[oc] + xb[(long long)oc * 1024 + n];
            }
        }
    }
}

// ---------------------------------------------------------------------------
extern "C" void kernel_launch(void* const* d_in, const int* in_sizes, int n_in,
                              void* d_out, int out_size, void* d_ws, size_t ws_size,
                              hipStream_t stream)
{
    const float* x  = (const float*)d_in[0];
    const float* gs = (const float*)d_in[1];
    const float* gb = (const float*)d_in[2];
    const float* wq = (const float*)d_in[3];
    const float* bq = (const float*)d_in[4];
    const float* wk = (const float*)d_in[5];
    const float* bk = (const float*)d_in[6];
    const float* wv = (const float*)d_in[7];
    const float* bv = (const float*)d_in[8];
    const float* wo = (const float*)d_in[9];
    const float* bo = (const float*)d_in[10];
    float* out = (float*)d_out;

    u8* p = (u8*)d_ws;
    u8* hT   = p; p += 8388608;            // [B] tiled h (pos rows, chan K)
    u8* q    = p; p += 8388608;            // [B] tiled q
    u8* k    = p; p += 8388608;            // [B] tiled k
    u8* v    = p; p += 8388608;            // [B] tiled v
    u8* wqkv = p; p += 786432;             // [1536,512] fp8 row-major
    float* bqkv = (float*)p; p += 6144;    // [1536]
    u8* wob  = p; p += 262144;             // tiled [512,512] fp8 (x 2^18)

    // GN (blocks 0..511) + weight convert (512..4607)
    setup_kernel<<<4608, 256, 0, stream>>>(x, gs, gb, wq, wk, wv, wo, bq, bk, bv,
                                           hT, wqkv, wob, bqkv);

    // fused qkv: stage-B-once GEMM, tiled fp8 in/out
    gemm_qkv<<<dim3(8, 12, 16), 256, 0, stream>>>(hT, wqkv, q, k, v, bqkv);

    // fused attention middle + output projection + residual (4-wave, prefetch)
    attn_out<<<dim3(512, 1, 1), 256, 0, stream>>>(q, k, v, wob, bo, x, out);
}

// Round 12
// 163.620 us; speedup vs baseline: 1.0541x; 1.0541x over previous
//
#include <hip/hip_runtime.h>
#include <hip/hip_bf16.h>
#include <cstdint>

typedef unsigned char u8;
typedef float floatx4 __attribute__((ext_vector_type(4)));
typedef int intx8 __attribute__((ext_vector_type(8)));

__device__ __forceinline__ void gld_lds16(const void* g, void* l) {
    __builtin_amdgcn_global_load_lds(
        (const __attribute__((address_space(1))) unsigned int*)g,
        (__attribute__((address_space(3))) unsigned int*)l, 16, 0, 0);
}

// fp8 e4m3 (OCP) converts
__device__ __forceinline__ u8 f2fp8(float v) {
    return (u8)(__builtin_amdgcn_cvt_pk_fp8_f32(v, v, 0, false) & 0xff);
}
__device__ __forceinline__ unsigned int pack4_fp8(float a, float b, float c, float d) {
    unsigned int u = __builtin_amdgcn_cvt_pk_fp8_f32(a, b, 0, false);
    u = __builtin_amdgcn_cvt_pk_fp8_f32(c, d, u, true);
    return u;
}

// 32B fragment: two swizzled 16B granules -> v8i32 (LDS, 128B rows)
__device__ __forceinline__ intx8 ld_frag(const u8* p, int lo, int hi) {
    uint4 a = *(const uint4*)(p + lo);
    uint4 b = *(const uint4*)(p + hi);
    intx8 r;
    r[0] = a.x; r[1] = a.y; r[2] = a.z; r[3] = a.w;
    r[4] = b.x; r[5] = b.y; r[6] = b.z; r[7] = b.w;
    return r;
}
// 32B fragment straight from global (contiguous; coalesced under tiled layout)
__device__ __forceinline__ intx8 ld_frag_g(const u8* p) {
    uint4 a = *(const uint4*)(p);
    uint4 b = *(const uint4*)(p + 16);
    intx8 r;
    r[0] = a.x; r[1] = a.y; r[2] = a.z; r[3] = a.w;
    r[4] = b.x; r[5] = b.y; r[6] = b.z; r[7] = b.w;
    return r;
}

// ---------------------------------------------------------------------------
// Tiled fp8 layouts (per batch, 512KB each):
//   hT,q,k : addr = rb*8192 + cb*512 + ln*32 + [0,32)   rb=pos/16, cb=chan/32
//   v      : addr = chb*16384 + mq*512 + ln*32 + [0,32) chb=chan/16, mq=pos/32
//   wob    : addr = (oc/16)*8192 + (c/32)*512 + (oc%16)*32 + c%32  [512x512]
// A wave's MFMA fragment load (4 q4-groups x 16 ln x 32B) is 2KB contiguous.
// wqkv stays ROW-major [1536x512] (consumed via swizzled LDS staging).
//
// __launch_bounds__ empirical rule (r5/8/9/10/11): VGPR cap = 256/arg2.
// attn_out: (256,2) [cap 128, ~7-reg spill] measured FASTER than (256,1)
// [VGPR 176, no spill, occupancy drop] — 45 vs 55 µs. Keep (256,2).
// ---------------------------------------------------------------------------

// ---------------------------------------------------------------------------
// Setup: blocks 0..511 = one-pass GroupNorm (x fp32 -> hT TILED fp8);
// blocks 512..4607 = weight convert (wqkv row-major; wob tiled).
// ---------------------------------------------------------------------------
__global__ __launch_bounds__(256) void setup_kernel(
    const float* __restrict__ x, const float* __restrict__ gs,
    const float* __restrict__ gb,
    const float* __restrict__ wq, const float* __restrict__ wk,
    const float* __restrict__ wv, const float* __restrict__ wo,
    const float* __restrict__ bq, const float* __restrict__ bk,
    const float* __restrict__ bv,
    u8* __restrict__ hT, u8* __restrict__ wqkv, u8* __restrict__ wob,
    float* __restrict__ bqkv)
{
    const int t = threadIdx.x;
    if (blockIdx.x >= 512) {
        int i = (blockIdx.x - 512) * 256 + t;   // 0 .. 1048575
        if (i < 786432) {
            int which = i >> 18;
            int off = i & 262143;
            const float* src = which == 0 ? wq : which == 1 ? wk : wv;
            wqkv[i] = f2fp8(src[off]);
        } else {
            int i2 = i - 786432;                // [512 x 512] -> tiled
            int row = i2 >> 9, col = i2 & 511;
            wob[(long long)(row >> 4) * 8192 + (col >> 5) * 512
                + (row & 15) * 32 + (col & 31)] = f2fp8(wo[i2] * 262144.0f);  // x 2^18
        }
        if (i < 1536)
            bqkv[i] = i < 512 ? bq[i] : (i < 1024 ? bk[i - 512] : bv[i - 1024]);
        return;
    }
    const int b = blockIdx.x >> 5;
    const int g = blockIdx.x & 31;
    const int wave = t >> 6, lane = t & 63;
    const float4* x4 = (const float4*)(x + ((long long)b * 512 + g * 16) * 1024);

    // one pass: 16 channels x 4 positions per thread, kept in registers
    float4 v[16];
    float s1 = 0.f, s2 = 0.f;
#pragma unroll
    for (int i = 0; i < 16; ++i) {
        v[i] = x4[i * 256 + t];
        s1 += v[i].x + v[i].y + v[i].z + v[i].w;
        s2 += v[i].x * v[i].x + v[i].y * v[i].y + v[i].z * v[i].z + v[i].w * v[i].w;
    }
#pragma unroll
    for (int m = 32; m; m >>= 1) {
        s1 += __shfl_xor(s1, m, 64);
        s2 += __shfl_xor(s2, m, 64);
    }
    __shared__ float red[2][4];
    __shared__ float stats[2];
    if (lane == 0) { red[0][wave] = s1; red[1][wave] = s2; }
    __syncthreads();
    if (t == 0) {
        float a = red[0][0] + red[0][1] + red[0][2] + red[0][3];
        float q = red[1][0] + red[1][1] + red[1][2] + red[1][3];
        float mu = a * (1.0f / 16384.0f);
        float var = q * (1.0f / 16384.0f) - mu * mu;
        stats[0] = mu;
        stats[1] = rsqrtf(var + 1e-5f);
    }
    __syncthreads();
    const float mu = stats[0], rs = stats[1];

#pragma unroll
    for (int i = 0; i < 16; ++i) {
        const float sc = gs[g * 16 + i] * rs;
        const float bi = gb[g * 16 + i] - mu * sc;
        v[i].x = v[i].x * sc + bi;
        v[i].y = v[i].y * sc + bi;
        v[i].z = v[i].z * sc + bi;
        v[i].w = v[i].w * sc + bi;
    }
    // TILED fp8 write: pos = 4t+r, chans g*16..g*16+15 = half of granule g>>1
    u8* hb = hT + (long long)b * 524288 + (g >> 1) * 512 + (g & 1) * 16;
#pragma unroll
    for (int r = 0; r < 4; ++r) {
        const int pos = 4 * t + r;
        uint4 o;
        o.x = pack4_fp8(v[0][r],  v[1][r],  v[2][r],  v[3][r]);
        o.y = pack4_fp8(v[4][r],  v[5][r],  v[6][r],  v[7][r]);
        o.z = pack4_fp8(v[8][r],  v[9][r],  v[10][r], v[11][r]);
        o.w = pack4_fp8(v[12][r], v[13][r], v[14][r], v[15][r]);
        *(uint4*)(hb + (long long)(pos >> 4) * 8192 + (pos & 15) * 32) = o;
    }
}

// ---------------------------------------------------------------------------
// QKV GEMM, stage-B-once: C[pos,oc] = sum_c hT[pos,c] * wqkv[oc,c].
// 128x128 tile, 4 waves 64x64. B-tile [128 oc x 512] staged to LDS ONCE via
// swizzled global_load_lds (16 chunks, 1 barrier); A-fragments direct from
// L2 (tiled hT, 2KB/wave coalesced); 64 MFMAs with no inner barriers.
// Epilogue = fused QKV fp8 (+bias) into tiled q/k/v layouts.
// ---------------------------------------------------------------------------
__global__ __launch_bounds__(256, 1) void gemm_qkv(
    const u8* __restrict__ A,          // hT tiled, stride 524288/batch
    const u8* __restrict__ B,          // wqkv row-major [1536 x 512]
    u8* __restrict__ Cq, u8* __restrict__ Ck, u8* __restrict__ Cv,
    const float* __restrict__ bias)
{
    __shared__ __align__(16) u8 smem[65536];   // B-tile; epilogue reuses [0,18432)
    const int tid = threadIdx.x;
    const int l = tid & 63;
    const int wave = tid >> 6;
    const int wm = wave >> 1, wn = wave & 1;
    const int bm = blockIdx.x, bn = blockIdx.y, b = blockIdx.z;

    const int q4 = l >> 4;
    const int ln = l & 15;
    const int glo = ((2 * q4) ^ (l & 7)) * 16;
    const int ghi = ((2 * q4 + 1) ^ (l & 7)) * 16;
    const int lo32 = ln * 32;

    // ---- stage B-tile: 16 chunks of [32 rows x 128 B], XOR'd granules ----
    const int srow = wave * 8 + (l >> 3);               // 0..31
    const int sg = ((l & 7) ^ ((l >> 3) & 7)) * 16;     // pre-swizzled source
    const u8* Bb = B + (long long)bn * 128 * 512;
    const int ldst = wave * 1024;                        // + lane*16 implicit
#pragma unroll
    for (int kc = 0; kc < 4; ++kc)
#pragma unroll
        for (int rc = 0; rc < 4; ++rc)
            gld_lds16(Bb + (long long)(rc * 32 + srow) * 512 + kc * 128 + sg,
                      smem + kc * 16384 + rc * 4096 + ldst);

    // hoist kc=0 A-fragments above the barrier (L2 latency overlaps staging)
    const u8* Ab = A + (long long)b * 524288 + (long long)(bm * 8 + wm * 4) * 8192;
    intx8 af0[4];
#pragma unroll
    for (int i = 0; i < 4; ++i)
        af0[i] = ld_frag_g(Ab + (long long)i * 8192 + q4 * 512 + lo32);

    __syncthreads();   // B-tile resident

    floatx4 acc[4][4] = {};
#pragma unroll
    for (int kc = 0; kc < 4; ++kc) {
        intx8 bfr[4];
#pragma unroll
        for (int j = 0; j < 4; ++j)
            bfr[j] = ld_frag(smem + kc * 16384 + (wn * 64 + j * 16 + ln) * 128,
                             glo, ghi);
#pragma unroll
        for (int i = 0; i < 4; ++i) {
            intx8 af = (kc == 0) ? af0[i]
                : ld_frag_g(Ab + (long long)i * 8192 + (kc * 4 + q4) * 512 + lo32);
#pragma unroll
            for (int j = 0; j < 4; ++j)
                acc[i][j] = __builtin_amdgcn_mfma_scale_f32_16x16x128_f8f6f4(
                    af, bfr[j], acc[i][j], 0, 0, 0, 127, 0, 127);
        }
    }

    __syncthreads();   // B-tile dead; epilogue may overwrite smem

    // ---------------- epilogue: fused QKV fp8 (+bias), tiled outputs ----------
    // C/D layout: col=lane&15, row=(lane>>4)*4+reg
    {
        const int which = bn >> 2;     // 0=q 1=k 2=v
        u8* tile = smem;               // q/k: [pos 128][chan,144]; v: [chan 128][pos,144]
#pragma unroll
        for (int i = 0; i < 4; ++i) {
            const int rl = wm * 64 + i * 16 + q4 * 4;
#pragma unroll
            for (int j = 0; j < 4; ++j) {
                const int cl = wn * 64 + j * 16 + ln;
                const float badd = bias[bn * 128 + cl];
                if (which == 2) {
                    // col-major fill: rows rl..rl+3 contiguous -> one packed u32
                    *(unsigned int*)(tile + cl * 144 + rl) =
                        pack4_fp8(acc[i][j][0] + badd, acc[i][j][1] + badd,
                                  acc[i][j][2] + badd, acc[i][j][3] + badd);
                } else {
#pragma unroll
                    for (int r = 0; r < 4; ++r)
                        tile[(rl + r) * 144 + cl] = f2fp8(acc[i][j][r] + badd);
                }
            }
        }
        __syncthreads();
        // Tiled write-out: per wave-iter 1KB contiguous.
        const int w2  = wave >> 1;                 // 0..1
        const int cbl = (wave & 1) * 2 + (l >> 5); // 0..3
        const int lnw = (l >> 1) & 15;
        const int g16 = (l & 1) * 16;
#pragma unroll
        for (int p = 0; p < 4; ++p) {
            const int rtile = p * 2 + w2;          // 0..7
            uint4 dd = *(const uint4*)(tile + (rtile * 16 + lnw) * 144 + cbl * 32 + g16);
            u8* dst;
            if (which == 0)
                dst = Cq + (long long)b * 524288 + (long long)(bm * 8 + rtile) * 8192
                      + ((bn & 3) * 4 + cbl) * 512 + lnw * 32 + g16;
            else if (which == 1)
                dst = Ck + (long long)b * 524288 + (long long)(bm * 8 + rtile) * 8192
                      + ((bn & 3) * 4 + cbl) * 512 + lnw * 32 + g16;
            else
                dst = Cv + (long long)b * 524288 + (long long)((bn & 3) * 8 + rtile) * 16384
                      + (long long)(bm * 4 + cbl) * 512 + lnw * 32 + g16;
            *(uint4*)dst = dd;
        }
    }
}

// ---------------------------------------------------------------------------
// Fused attention + output projection (4-wave, k-prefetch) — round-10 best
// config: __launch_bounds__(256,2) (VGPR 128, ~7-reg spill, 45 µs measured;
// (256,1) regressed to 55 µs via occupancy loss).
// Per m-tile: QK (kreg, load-free) -> issue vA -> exp -> E tile (dbuf) ->
// barrier -> prefetch kreg(mt+1) -> PV (vA/vB direct L2).
// Phase 2: hv -> fp8 swizzled LDS, out = wo_s . hv^T + bo + x.
// ---------------------------------------------------------------------------
__global__ __launch_bounds__(256, 2) void attn_out(
    const u8* __restrict__ qg, const u8* __restrict__ kg,
    const u8* __restrict__ vg, const u8* __restrict__ wot,
    const float* __restrict__ bo, const float* __restrict__ xg,
    float* __restrict__ outg)
{
    __shared__ __align__(16) u8 smem[25088];  // E dbuf 8K | psum 512 | HV 16K
    const int tid = threadIdx.x;
    const int l = tid & 63;
    const int w = tid >> 6;
    // XCD-aware swizzle: all 32 q-blocks of a batch pair land on one XCD (d%8)
    const int d = blockIdx.x;
    const int b  = (d & 7) * 2 + ((d >> 8) & 1);
    const int bq = (d >> 3) & 31;

    const u8* qb = qg + (long long)b * 524288 + (long long)(bq * 2) * 8192;
    const u8* kb = kg + (long long)b * 524288;
    const u8* vb = vg + (long long)b * 524288;

    const int q4 = l >> 4;
    const int ln = l & 15;
    const int glo = ((2 * q4) ^ (l & 7)) * 16;
    const int ghi = ((2 * q4 + 1) ^ (l & 7)) * 16;
    const int lo32 = ln * 32;

    // q -> registers once (tiled: rb = bq*2 + j, cb = kc*4 + q4)
    intx8 qf[2][4];
#pragma unroll
    for (int j = 0; j < 2; ++j)
#pragma unroll
        for (int kc = 0; kc < 4; ++kc)
            qf[j][kc] = ld_frag_g(qb + j * 8192 + (kc * 4 + q4) * 512 + lo32);

    // k register double-buffer: fragments for the CURRENT m-tile
    intx8 kreg[2][4];
#pragma unroll
    for (int i = 0; i < 2; ++i)
#pragma unroll
        for (int kc = 0; kc < 4; ++kc)
            kreg[i][kc] = ld_frag_g(kb + (long long)(w * 2 + i) * 8192
                                       + (kc * 4 + q4) * 512 + lo32);

    floatx4 acc_pv[8][2] = {};
    float psum[2] = {0.f, 0.f};
    const float scale = 0.044194173824159216f;   // 1/sqrt(512)

    for (int mt = 0; mt < 8; ++mt) {
        u8* E = smem + (mt & 1) * 4096;
        // ---- QK^T: all operands in registers, zero loads ----
        floatx4 acc_s[2][2] = {};
#pragma unroll
        for (int kc = 0; kc < 4; ++kc)
#pragma unroll
            for (int i = 0; i < 2; ++i)
#pragma unroll
                for (int j = 0; j < 2; ++j)
                    acc_s[i][j] = __builtin_amdgcn_mfma_scale_f32_16x16x128_f8f6f4(
                        kreg[i][kc], qf[j][kc], acc_s[i][j], 0, 0, 0, 127, 0, 127);
        // ---- issue v loads early (latency hides under exp + barrier) ----
        intx8 vfA[4], vfB[4];
        const u8* vrow = vb + (long long)(w * 8) * 16384 + (mt * 4 + q4) * 512 + lo32;
#pragma unroll
        for (int i = 0; i < 4; ++i)
            vfA[i] = ld_frag_g(vrow + (long long)i * 16384);
        // ---- exp + pack -> swizzled E tile [32 n x 128 m] ----
#pragma unroll
        for (int i = 0; i < 2; ++i) {
#pragma unroll
            for (int j = 0; j < 2; ++j) {
                float e0 = __expf(acc_s[i][j][0] * scale);
                float e1 = __expf(acc_s[i][j][1] * scale);
                float e2 = __expf(acc_s[i][j][2] * scale);
                float e3 = __expf(acc_s[i][j][3] * scale);
                psum[j] += e0 + e1 + e2 + e3;
                const int n = j * 16 + ln;
                const int m0 = w * 32 + i * 16 + q4 * 4;
                *(unsigned int*)(E + n * 128 + (m0 ^ ((n & 7) * 16))) =
                    pack4_fp8(e0 * 0.25f, e1 * 0.25f, e2 * 0.25f, e3 * 0.25f);
            }
        }
        __syncthreads();          // E visible; dbuf makes this the ONLY barrier
        // ---- prefetch NEXT m-tile's k fragments (hide under PV MFMAs) ----
        if (mt < 7) {
            const u8* kn = kb + (long long)((mt + 1) * 8 + w * 2) * 8192
                              + q4 * 512 + lo32;
#pragma unroll
            for (int i = 0; i < 2; ++i)
#pragma unroll
                for (int kc = 0; kc < 4; ++kc)
                    kreg[i][kc] = ld_frag_g(kn + (long long)i * 8192 + kc * 2048);
        }
        // ---- PV: acc_pv[c,n] += v[c,m] . E[n,m] ----
#pragma unroll
        for (int i = 0; i < 4; ++i)
            vfB[i] = ld_frag_g(vrow + (long long)(i + 4) * 16384);
        intx8 ef[2];
#pragma unroll
        for (int j = 0; j < 2; ++j)
            ef[j] = ld_frag(E + (j * 16 + ln) * 128, glo, ghi);
#pragma unroll
        for (int i = 0; i < 4; ++i)
#pragma unroll
            for (int j = 0; j < 2; ++j)
                acc_pv[i][j] = __builtin_amdgcn_mfma_scale_f32_16x16x128_f8f6f4(
                    vfA[i], ef[j], acc_pv[i][j], 0, 0, 0, 127, 0, 127);
#pragma unroll
        for (int i = 0; i < 4; ++i)
#pragma unroll
            for (int j = 0; j < 2; ++j)
                acc_pv[i + 4][j] = __builtin_amdgcn_mfma_scale_f32_16x16x128_f8f6f4(
                    vfB[i], ef[j], acc_pv[i + 4][j], 0, 0, 0, 127, 0, 127);
    }

    // psum: sum the 4 q4-groups (lanes ^16, ^32), then across waves via LDS
#pragma unroll
    for (int j = 0; j < 2; ++j) {
        psum[j] += __shfl_xor(psum[j], 16, 64);
        psum[j] += __shfl_xor(psum[j], 32, 64);
    }
    float* sb = (float*)(smem + 8192);   // [4 waves][32 n]
    if (l < 16) {
        sb[w * 32 + l]      = psum[0];
        sb[w * 32 + 16 + l] = psum[1];
    }
    __syncthreads();
    float rln[2];
#pragma unroll
    for (int j = 0; j < 2; ++j) {
        const int n = j * 16 + ln;
        rln[j] = 4.0f / (sb[n] + sb[32 + n] + sb[64 + n] + sb[96 + n]);
    }

    // ---- Phase 2a: hv -> fp8 swizzled LDS subtiles (per wave: 128 chans) ----
    u8* HV = smem + 8704;
#pragma unroll
    for (int i = 0; i < 8; ++i) {
#pragma unroll
        for (int j = 0; j < 2; ++j) {
            const int n = j * 16 + ln;
            const int m0 = i * 16 + q4 * 4;   // byte offset within subtile row
            *(unsigned int*)(HV + w * 4096 + n * 128 + (m0 ^ ((n & 7) * 16))) =
                pack4_fp8(acc_pv[i][j][0] * rln[j], acc_pv[i][j][1] * rln[j],
                          acc_pv[i][j][2] * rln[j], acc_pv[i][j][3] * rln[j]);
        }
    }
    // hoist kc=0 wo fragments above the barrier (L2 latency overlaps sync)
    intx8 wo0[2];
#pragma unroll
    for (int rb = 0; rb < 2; ++rb)
        wo0[rb] = ld_frag_g(wot + (long long)(w * 8 + rb) * 8192 + q4 * 512 + lo32);
    __syncthreads();

    // ---- Phase 2b: out = wo_s . hv^T: per wave 128 oc x 32 n, K=512 ----
    floatx4 acc2[8][2] = {};
#pragma unroll
    for (int kc = 0; kc < 4; ++kc) {
        intx8 hvf[2];
#pragma unroll
        for (int j = 0; j < 2; ++j)
            hvf[j] = ld_frag(HV + kc * 4096 + (j * 16 + ln) * 128, glo, ghi);
#pragma unroll
        for (int rb = 0; rb < 8; ++rb) {
            intx8 wof = (kc == 0 && rb < 2) ? wo0[rb]
                : ld_frag_g(wot + (long long)(w * 8 + rb) * 8192
                                + (kc * 4 + q4) * 512 + lo32);
#pragma unroll
            for (int j = 0; j < 2; ++j)
                acc2[rb][j] = __builtin_amdgcn_mfma_scale_f32_16x16x128_f8f6f4(
                    wof, hvf[j], acc2[rb][j], 0, 0, 0, 127, 0, 127);
        }
    }

    // ---- epilogue: out[b][oc][n] = acc2*2^-18 + bo[oc] + x[b][oc][n] ----
    const float osc = 3.814697265625e-06f;       // 2^-18
    const float* xb = xg + (long long)b * 524288;
    float* og = outg + (long long)b * 524288;
    const int n0 = bq * 32;
#pragma unroll
    for (int rb = 0; rb < 8; ++rb) {
        const int oc0 = w * 128 + rb * 16 + q4 * 4;
#pragma unroll
        for (int j = 0; j < 2; ++j) {
            const int n = n0 + j * 16 + ln;
#pragma unroll
            for (int r = 0; r < 4; ++r) {
                const int oc = oc0 + r;
                og[(long long)oc * 1024 + n] =
                    acc2[rb][j][r] * osc + bo[oc] + xb[(long long)oc * 1024 + n];
            }
        }
    }
}

// ---------------------------------------------------------------------------
extern "C" void kernel_launch(void* const* d_in, const int* in_sizes, int n_in,
                              void* d_out, int out_size, void* d_ws, size_t ws_size,
                              hipStream_t stream)
{
    const float* x  = (const float*)d_in[0];
    const float* gs = (const float*)d_in[1];
    const float* gb = (const float*)d_in[2];
    const float* wq = (const float*)d_in[3];
    const float* bq = (const float*)d_in[4];
    const float* wk = (const float*)d_in[5];
    const float* bk = (const float*)d_in[6];
    const float* wv = (const float*)d_in[7];
    const float* bv = (const float*)d_in[8];
    const float* wo = (const float*)d_in[9];
    const float* bo = (const float*)d_in[10];
    float* out = (float*)d_out;

    u8* p = (u8*)d_ws;
    u8* hT   = p; p += 8388608;            // [B] tiled h (pos rows, chan K)
    u8* q    = p; p += 8388608;            // [B] tiled q
    u8* k    = p; p += 8388608;            // [B] tiled k
    u8* v    = p; p += 8388608;            // [B] tiled v
    u8* wqkv = p; p += 786432;             // [1536,512] fp8 row-major
    float* bqkv = (float*)p; p += 6144;    // [1536]
    u8* wob  = p; p += 262144;             // tiled [512,512] fp8 (x 2^18)

    // GN (blocks 0..511) + weight convert (512..4607)
    setup_kernel<<<4608, 256, 0, stream>>>(x, gs, gb, wq, wk, wv, wo, bq, bk, bv,
                                           hT, wqkv, wob, bqkv);

    // fused qkv: stage-B-once GEMM, tiled fp8 in/out
    gemm_qkv<<<dim3(8, 12, 16), 256, 0, stream>>>(hT, wqkv, q, k, v, bqkv);

    // fused attention middle + output projection + residual (4-wave, prefetch)
    attn_out<<<dim3(512, 1, 1), 256, 0, stream>>>(q, k, v, wob, bo, x, out);
}